// Round 5
// baseline (6535.439 us; speedup 1.0000x reference)
//
#include <hip/hip_runtime.h>
#include <hip/hip_bf16.h>

// 5-layer GNN encoder x2 branches + projector + mean-pool + L2norm + logits.
// Round 11: tall GEMM tile 256x128 (was 128x128). R9 (issue-early) and R10
// (counted vmcnt) were BOTH null => the limiter is a fixed per-block-K-step
// latency tax, not the sync structure (bottom-up MFMA/LDS/store throughput
// accounts for <40% of measured time). Counter: halve the number of
// block-K-steps by doubling per-step work. M-tile 256: 4 waves each own
// 64 rows x 128 cols (acc 4x8), A staged once per K-step for 2x output,
// B L2 re-reads halve. LDS 64KB (2 blocks/CU), ~180 VGPR (2 waves/SIMD).
// Per-output FP sequence unchanged; BN psum slots now [391][768] (still
// fixed-slot deterministic). Counted-vmcnt loop kept (8 loads/step).
//
// d_ws layout (bytes):
//   h    bf16 [N,300]  @ 0            pre-BN layer output
//   agg  bf16 [N,320]  @ 60,000,000   K-padded zeros in 300..319
//   hid  bf16 [N,600]  @ 124,000,000  (reused: BN(h) copy; then f-splits for logits)
//   guard 256B zero    @ 244,000,000  (protects GEMM2 last-row K-overrun)
//   f0   f32  [4096,300] @ 244,000,256
//   f1   f32  [4096,300] @ 248,915,456   total 253,830,656
// d_out doubles as scratch (CSR + packed + stats + combo + split weights +
// psum/part2), all consumed before the final logits GEMM overwrites it.

#define EMB 300
#define EMBC 75       // 300/4 chunks (h pitch 300)
#define AGGP 320      // agg row pitch (elems)
#define AGGC 80
#define HID 600
#define NGRAPH 4096
#define BN_EPS 1e-5f
#define INV_TEMP 25.0f
#define NRED 24       // stage-1 stat-reduction blocks

typedef __hip_bfloat16 bf16;
struct __align__(8) bf4 { bf16 x, y, z, w; };
typedef __attribute__((ext_vector_type(8))) short short8;
typedef __attribute__((ext_vector_type(4))) float float4v;

__device__ inline float b2f(bf16 v) { return __bfloat162float(v); }
__device__ inline bf16 f2b(float v) { return __float2bfloat16(v); }
__device__ inline unsigned short f2bu(float f) {
    bf16 b = __float2bfloat16(f); unsigned short u; __builtin_memcpy(&u, &b, 2); return u;
}

// async global->LDS, 16 bytes per lane; LDS dest = uniform base + lane*16
typedef const unsigned int __attribute__((address_space(1)))* gas_t;
typedef unsigned int __attribute__((address_space(3)))* las_t;
__device__ __forceinline__ void gl_lds16(const unsigned short* g, unsigned short* l) {
    __builtin_amdgcn_global_load_lds((gas_t)g, (las_t)l, 16, 0, 0);
}

// ---------------- small utility ----------------

__global__ void k_zero_f(float* __restrict__ p, int n) {
    int i = blockIdx.x * blockDim.x + threadIdx.x;
    if (i < n) p[i] = 0.f;
}
__global__ void k_zero_i(int* __restrict__ p, int n) {
    int i = blockIdx.x * blockDim.x + threadIdx.x;
    if (i < n) p[i] = 0;
}

// ---------------- weight split: W[K][N] f32 -> Wt_hi/lo[Npad][Kpad] bf16 ----------------

__global__ void k_split(const float* __restrict__ W, int K, int N, int Kpad, int Npad,
                        unsigned short* __restrict__ hi, unsigned short* __restrict__ lo) {
    int idx = blockIdx.x * blockDim.x + threadIdx.x;
    if (idx >= Npad * Kpad) return;
    int n = idx / Kpad, k = idx % Kpad;
    float v = (n < N && k < K) ? W[(size_t)k * N + n] : 0.f;
    bf16 h = __float2bfloat16(v);
    float rem = v - __bfloat162float(h);
    bf16 l = __float2bfloat16(rem);
    unsigned short hu, lu;
    __builtin_memcpy(&hu, &h, 2); __builtin_memcpy(&lu, &l, 2);
    hi[idx] = hu; lo[idx] = lu;
}

// f[G,300] f32 -> hi/lo [G,320] bf16 (pad zero)
__global__ void k_fsplit(const float* __restrict__ f, unsigned short* __restrict__ hi,
                         unsigned short* __restrict__ lo, int G) {
    int idx = blockIdx.x * blockDim.x + threadIdx.x;
    if (idx >= G * AGGP) return;
    int g = idx / AGGP, c = idx % AGGP;
    float v = (c < EMB) ? f[(size_t)g * EMB + c] : 0.f;
    bf16 h = __float2bfloat16(v);
    float rem = v - __bfloat162float(h);
    unsigned short hu; __builtin_memcpy(&hu, &h, 2);
    hi[idx] = hu;
    lo[idx] = f2bu(rem);
}

// ---------------- CSR build (dst-sorted edge ids) ----------------

__global__ void k_hist(const int* __restrict__ ei, int* __restrict__ deg, int E) {
    int e = blockIdx.x * blockDim.x + threadIdx.x;
    if (e < E) atomicAdd(&deg[ei[E + e]], 1);
}

__global__ void k_chunksum(const int* __restrict__ deg, int* __restrict__ csum, int total) {
    __shared__ int s[256];
    int t = threadIdx.x, i = blockIdx.x * 256 + t;
    s[t] = (i < total) ? deg[i] : 0;
    __syncthreads();
    for (int off = 128; off > 0; off >>= 1) {
        if (t < off) s[t] += s[t + off];
        __syncthreads();
    }
    if (t == 0) csum[blockIdx.x] = s[0];
}

__global__ void k_scanchunks(const int* __restrict__ csum, int* __restrict__ coff, int n) {
    if (threadIdx.x == 0) {
        int acc = 0;
        for (int b = 0; b < n; ++b) { coff[b] = acc; acc += csum[b]; }
    }
}

__global__ void k_scan2(const int* __restrict__ deg, const int* __restrict__ coff,
                        int* __restrict__ rowstart, int total) {
    __shared__ int s[256];
    int t = threadIdx.x, b = blockIdx.x, i = b * 256 + t;
    int v = (i < total) ? deg[i] : 0;
    s[t] = v;
    __syncthreads();
    for (int off = 1; off < 256; off <<= 1) {
        int u = (t >= off) ? s[t - off] : 0;
        __syncthreads();
        s[t] += u;
        __syncthreads();
    }
    if (i < total) rowstart[i] = coff[b] + s[t] - v;
}

__global__ void k_initcursor(const int* __restrict__ rowstart, int* __restrict__ cur, int N) {
    int i = blockIdx.x * blockDim.x + threadIdx.x;
    if (i < N) cur[i] = rowstart[i];
}

__global__ void k_fill(const int* __restrict__ ei, int* __restrict__ cur,
                       int* __restrict__ esorted, int E) {
    int e = blockIdx.x * blockDim.x + threadIdx.x;
    if (e < E) {
        int p = atomicAdd(&cur[ei[E + e]], 1);
        esorted[p] = e;
    }
}

// packed[p] = src | (combo<<17), combo = a0*3+a1 (18 combos; self-loop=12)
__global__ void k_pack(const int* __restrict__ ei, const int* __restrict__ ea,
                       const int* __restrict__ esorted, int* __restrict__ packed, int E) {
    int p = blockIdx.x * blockDim.x + threadIdx.x;
    if (p >= E) return;
    int e = esorted[p];
    int s = ei[e];
    int cb = ea[2 * e] * 3 + ea[2 * e + 1];
    packed[p] = s | (cb << 17);
}

// canonical per-bucket order: insertion-sort packed values within each node's
// CSR range -> deterministic fp32 aggregation sum order across calls.
__global__ void k_sortb(const int* __restrict__ rowstart, int* __restrict__ packed, int N) {
    int n = blockIdx.x * blockDim.x + threadIdx.x;
    if (n >= N) return;
    int p0 = rowstart[n], p1 = rowstart[n + 1];
    for (int i = p0 + 1; i < p1; ++i) {
        int v = packed[i];
        int j = i - 1;
        while (j >= p0 && packed[j] > v) { packed[j + 1] = packed[j]; --j; }
        packed[j + 1] = v;
    }
}

__global__ void k_gstart(const int* __restrict__ batch, int* __restrict__ gstart, int N) {
    int g = blockIdx.x * blockDim.x + threadIdx.x;
    if (g > NGRAPH) return;
    int lo = 0, hi = N;
    while (lo < hi) { int mid = (lo + hi) >> 1; if (batch[mid] < g) lo = mid + 1; else hi = mid; }
    gstart[g] = lo;
}

// per-layer combo table: cmb[cb][300] = e1[cb/3] + e2[cb%3]  (fp32)
__global__ void k_combo(const float4* __restrict__ e1, const float4* __restrict__ e2,
                        float4* __restrict__ cmb) {
    int t = blockIdx.x * blockDim.x + threadIdx.x;
    if (t >= 18 * EMBC) return;
    int cb = t / EMBC, j = t % EMBC;
    float4 u = e1[(cb / 3) * EMBC + j];
    float4 v = e2[(cb % 3) * EMBC + j];
    float4 r; r.x = u.x + v.x; r.y = u.y + v.y; r.z = u.z + v.z; r.w = u.w + v.w;
    cmb[t] = r;
}

// ---------------- node init & aggregation (with fused BN affine) ----------------

__global__ void k_init_h(const int* __restrict__ x,
                         const float4* __restrict__ ae1,
                         const float4* __restrict__ ae2,
                         bf4* __restrict__ h4, int N) {
    int idx = blockIdx.x * blockDim.x + threadIdx.x;
    if (idx >= N * EMBC) return;
    int i = idx / EMBC, j = idx % EMBC;
    int a0 = x[2 * i], a1 = x[2 * i + 1];
    float4 u = ae1[a0 * EMBC + j];
    float4 v = ae2[a1 * EMBC + j];
    bf4 r = { f2b(u.x + v.x), f2b(u.y + v.y), f2b(u.z + v.z), f2b(u.w + v.w) };
    h4[idx] = r;
}

// agg[n] = act(h[n]) + cmb[12] + sum_p ( act(h[src(p)]) + cmb[combo(p)] )
__global__ void k_aggregate(const bf4* __restrict__ h4,
                            const int* __restrict__ packed,
                            const float4* __restrict__ cmb,   // [18,75]
                            const int* __restrict__ rowstart,
                            const float* __restrict__ stats, int use_aff,
                            bf4* __restrict__ agg4, int N) {
    int idx = blockIdx.x * blockDim.x + threadIdx.x;
    if (idx >= N * AGGC) return;
    int n = idx / AGGC, j = idx % AGGC;
    if (j >= EMBC) {
        bf4 z = { f2b(0.f), f2b(0.f), f2b(0.f), f2b(0.f) };
        agg4[idx] = z;
        return;
    }
    float4 sc = make_float4(1.f, 1.f, 1.f, 1.f);
    float4 sh = make_float4(0.f, 0.f, 0.f, 0.f);
    if (use_aff) {
        sc = ((const float4*)stats)[j];
        sh = ((const float4*)(stats + EMB))[j];
    }
    bf4 hv = h4[(size_t)n * EMBC + j];
    float hx = b2f(hv.x), hy = b2f(hv.y), hz = b2f(hv.z), hw = b2f(hv.w);
    if (use_aff) {
        hx = fmaxf(hx * sc.x + sh.x, 0.f); hy = fmaxf(hy * sc.y + sh.y, 0.f);
        hz = fmaxf(hz * sc.z + sh.z, 0.f); hw = fmaxf(hw * sc.w + sh.w, 0.f);
    }
    float4 s0 = cmb[12 * EMBC + j];      // self-loop combo (edge_attr [4,0])
    float ax = hx + s0.x, ay = hy + s0.y, az = hz + s0.z, aw = hw + s0.w;
    int p0 = rowstart[n], p1 = rowstart[n + 1];
    for (int p = p0; p < p1; ++p) {
        int u = packed[p];
        int s = u & 131071;
        int cb = u >> 17;
        bf4 hs = h4[(size_t)s * EMBC + j];
        float gx = b2f(hs.x), gy = b2f(hs.y), gz = b2f(hs.z), gw = b2f(hs.w);
        if (use_aff) {
            gx = fmaxf(gx * sc.x + sh.x, 0.f); gy = fmaxf(gy * sc.y + sh.y, 0.f);
            gz = fmaxf(gz * sc.z + sh.z, 0.f); gw = fmaxf(gw * sc.w + sh.w, 0.f);
        }
        float4 cv = cmb[cb * EMBC + j];
        ax += gx + cv.x; ay += gy + cv.y;
        az += gz + cv.z; aw += gw + cv.w;
    }
    bf4 r = { f2b(ax), f2b(ay), f2b(az), f2b(aw) };
    agg4[idx] = r;
}

// BN(h) copy for projector: dst[N,320] = scale*h + shift (no relu), pad zeroed
__global__ void k_bncopy(const bf4* __restrict__ h4, const float* __restrict__ stats,
                         bf4* __restrict__ dst, int N) {
    int idx = blockIdx.x * blockDim.x + threadIdx.x;
    if (idx >= N * AGGC) return;
    int n = idx / AGGC, j = idx % AGGC;
    if (j >= EMBC) {
        bf4 z = { f2b(0.f), f2b(0.f), f2b(0.f), f2b(0.f) };
        dst[idx] = z;
        return;
    }
    float4 sc = ((const float4*)stats)[j];
    float4 sh = ((const float4*)(stats + EMB))[j];
    bf4 v = h4[(size_t)n * EMBC + j];
    bf4 r = { f2b(b2f(v.x) * sc.x + sh.x), f2b(b2f(v.y) * sc.y + sh.y),
              f2b(b2f(v.z) * sc.z + sh.z), f2b(b2f(v.w) * sc.w + sh.w) };
    dst[idx] = r;
}

// ---------------- MFMA GEMM: C_bf16[M,Nc] = A_bf16[M,K] @ (Bhi+Blo)^T + bias --------
// Round 11: tile 256x128, GBK=32, double-buffered (64 KB LDS => 2 blocks/CU).
// 4 waves stacked in M: wave wv owns rows [64wv,64wv+64) x all 128 cols
// (acc[4][8]). Counted-vmcnt loop: 8 gl_lds16/wave/step; wait vmcnt(8).
// 64B-row LDS swizzle: store chunk (lane&3)^((lane>>3)&3); read
// pc = quad^((l16>>1)&3). Per-output-element FP sequence identical to
// round 10 (same k order, same hi/lo chain).

#define GBM 256
#define GBN 128
#define GBK 32

__global__ __launch_bounds__(256)
void k_gemm_mfma(const unsigned short* __restrict__ A, int lda, int Kpad,
                 const unsigned short* __restrict__ Bhi,
                 const unsigned short* __restrict__ Blo, int ldb,
                 const float* __restrict__ bias,
                 unsigned short* __restrict__ C, int ldc, int M, int Nc, int relu,
                 float* __restrict__ psum, int do_stats) {
    __shared__ unsigned short As[2][GBM][GBK];   // 32 KB (reused as cred)
    __shared__ unsigned short Bh[2][GBN][GBK];   // 16 KB
    __shared__ unsigned short Bl[2][GBN][GBK];   // 16 KB

    int tid = threadIdx.x;
    int wv = tid >> 6, lane = tid & 63;
    int quad = lane >> 4, l16 = lane & 15;

    // staging lane mapping: 4 lanes/row, chunk XOR-swizzled by row pair
    int srow = lane >> 2;                     // 0..15
    int gch = (lane & 3) ^ ((lane >> 3) & 3); // global 8-elem chunk
    // read swizzle
    int pc = quad ^ ((l16 >> 1) & 3);

    // XCD swizzle: col-tiles of one row-block get linear ids equal mod 8
    int ncols = gridDim.x, nrows = gridDim.y;
    int lin = blockIdx.y * ncols + blockIdx.x;
    int g = lin / (8 * ncols);
    int rem = lin - g * 8 * ncols;
    int rows_in = min(8, nrows - g * 8);
    int colb = rem / rows_in;
    int rowb = g * 8 + (rem - colb * rows_in);
    int row0 = rowb * GBM;
    int col0 = colb * GBN;

    // per-lane staging source bases: wave wv stages A rows [64wv,64wv+64),
    // B rows [32wv,32wv+32)
    const unsigned short* Asrc[4];
    #pragma unroll
    for (int j = 0; j < 4; ++j) {
        int r = 64 * wv + 16 * j + srow;
        Asrc[j] = A + (size_t)min(row0 + r, M - 1) * lda + gch * 8;
    }
    const unsigned short* Bsrc[2];
    #pragma unroll
    for (int j = 0; j < 2; ++j) {
        int r = 32 * wv + 16 * j + srow;
        Bsrc[j] = Bhi + (size_t)(col0 + r) * ldb + gch * 8;
    }
    const size_t dBL = (size_t)(Blo - Bhi);

    float4v acc[4][8];
    #pragma unroll
    for (int i = 0; i < 4; ++i)
        #pragma unroll
        for (int j = 0; j < 8; ++j) acc[i][j] = (float4v){0.f, 0.f, 0.f, 0.f};

    const int ntk = Kpad / GBK;

    // prologue: stage tiles 0 and 1 (16 loads in flight per wave)
    #pragma unroll
    for (int j = 0; j < 4; ++j)
        gl_lds16(Asrc[j], &As[0][64 * wv + 16 * j][0]);
    #pragma unroll
    for (int j = 0; j < 2; ++j) {
        gl_lds16(Bsrc[j], &Bh[0][32 * wv + 16 * j][0]);
        gl_lds16(Bsrc[j] + dBL, &Bl[0][32 * wv + 16 * j][0]);
    }
    if (ntk > 1) {
        #pragma unroll
        for (int j = 0; j < 4; ++j)
            gl_lds16(Asrc[j] + GBK, &As[1][64 * wv + 16 * j][0]);
        #pragma unroll
        for (int j = 0; j < 2; ++j) {
            gl_lds16(Bsrc[j] + GBK, &Bh[1][32 * wv + 16 * j][0]);
            gl_lds16(Bsrc[j] + GBK + dBL, &Bl[1][32 * wv + 16 * j][0]);
        }
    }

    for (int t = 0; t < ntk; ++t) {
        int cur = t & 1;
        // wait own tile-t loads (8); tile-t+1's 8 stay in flight
        if (t + 1 < ntk) {
            asm volatile("s_waitcnt vmcnt(8)" ::: "memory");
        } else {
            asm volatile("s_waitcnt vmcnt(0)" ::: "memory");
        }
        __builtin_amdgcn_s_barrier();          // all waves' tile-t in LDS
        __builtin_amdgcn_sched_barrier(0);
        // compute current tile: wave wv rows [64wv..64wv+64) x cols [0..128)
        short8 a[4];
        #pragma unroll
        for (int mt = 0; mt < 4; ++mt)
            a[mt] = *(const short8*)(&As[cur][64 * wv + mt * 16 + l16][pc * 8]);
        #pragma unroll
        for (int ntl = 0; ntl < 8; ++ntl) {
            short8 bh = *(const short8*)(&Bh[cur][ntl * 16 + l16][pc * 8]);
            short8 bl = *(const short8*)(&Bl[cur][ntl * 16 + l16][pc * 8]);
            #pragma unroll
            for (int mt = 0; mt < 4; ++mt) {
                acc[mt][ntl] = __builtin_amdgcn_mfma_f32_16x16x32_bf16(a[mt], bh, acc[mt][ntl], 0, 0, 0);
                acc[mt][ntl] = __builtin_amdgcn_mfma_f32_16x16x32_bf16(a[mt], bl, acc[mt][ntl], 0, 0, 0);
            }
        }
        __builtin_amdgcn_s_barrier();          // all waves done reading buf[cur]
        __builtin_amdgcn_sched_barrier(0);
        // restage consumed buffer with tile t+2 (in flight across next barrier)
        if (t + 2 < ntk) {
            int k2 = (t + 2) * GBK;
            #pragma unroll
            for (int j = 0; j < 4; ++j)
                gl_lds16(Asrc[j] + k2, &As[cur][64 * wv + 16 * j][0]);
            #pragma unroll
            for (int j = 0; j < 2; ++j) {
                gl_lds16(Bsrc[j] + k2, &Bh[cur][32 * wv + 16 * j][0]);
                gl_lds16(Bsrc[j] + k2 + dBL, &Bl[cur][32 * wv + 16 * j][0]);
            }
        }
    }

    // epilogue: C/D layout col=lane&15, row=quad*4+reg
    float sv[8], qv[8];
    #pragma unroll
    for (int ntl = 0; ntl < 8; ++ntl) { sv[ntl] = 0.f; qv[ntl] = 0.f; }
    #pragma unroll
    for (int mt = 0; mt < 4; ++mt) {
        int rbase = row0 + 64 * wv + mt * 16 + quad * 4;
        #pragma unroll
        for (int ntl = 0; ntl < 8; ++ntl) {
            int c = col0 + ntl * 16 + l16;
            if (c >= Nc) continue;
            float bs = bias[c];
            #pragma unroll
            for (int i = 0; i < 4; ++i) {
                int r = rbase + i;
                if (r >= M) continue;
                float v = acc[mt][ntl][i] + bs;
                if (relu) v = fmaxf(v, 0.f);
                if (do_stats) { sv[ntl] += v; qv[ntl] += v * v; }
                C[(size_t)r * ldc + c] = f2bu(v);
            }
        }
    }
    if (do_stats) {
        float* cred = (float*)(&As[0][0][0]);   // 4 waves x (128 s + 128 q) floats
        #pragma unroll
        for (int ntl = 0; ntl < 8; ++ntl) {
            float s = sv[ntl], q = qv[ntl];
            s += __shfl_down(s, 32, 64); s += __shfl_down(s, 16, 64);
            q += __shfl_down(q, 32, 64); q += __shfl_down(q, 16, 64);
            if (quad == 0) {
                cred[wv * 256 + ntl * 16 + l16] = s;
                cred[wv * 256 + 128 + ntl * 16 + l16] = q;
            }
        }
        __syncthreads();
        if (tid < 128) {
            // per-row-block partial: psum[rowb][c] = s, psum[rowb][384+c] = q
            int c = col0 + tid;
            float s = cred[0 * 256 + tid] + cred[1 * 256 + tid]
                    + cred[2 * 256 + tid] + cred[3 * 256 + tid];
            float q = cred[0 * 256 + 128 + tid] + cred[1 * 256 + 128 + tid]
                    + cred[2 * 256 + 128 + tid] + cred[3 * 256 + 128 + tid];
            psum[(size_t)rowb * 768 + c] = s;
            psum[(size_t)rowb * 768 + 384 + c] = q;
        }
    }
}

// ---------------- logits MFMA: out = scale * (Ah+Al) @ (Bh+Bl)^T  (ll skipped) ----

__global__ __launch_bounds__(256)
void k_logits(const unsigned short* __restrict__ Ahg, const unsigned short* __restrict__ Alg,
              const unsigned short* __restrict__ Bhg, const unsigned short* __restrict__ Blg,
              float* __restrict__ C, float scale) {
    __shared__ unsigned short sAh[64][64];
    __shared__ unsigned short sAl[64][64];
    __shared__ unsigned short sBh[128][64];
    __shared__ unsigned short sBl[128][64];

    int tid = threadIdx.x;
    int wv = tid >> 6, lane = tid & 63;
    int quad = lane >> 4, l16 = lane & 15;
    int lrow = lane >> 3;
    int gchunk = (lane & 7) ^ lrow;
    int sw = lane & 7;
    int row0 = blockIdx.y * 64;
    int col0 = blockIdx.x * 128;

    float4v acc[8];
    #pragma unroll
    for (int j = 0; j < 8; ++j) acc[j] = (float4v){0.f, 0.f, 0.f, 0.f};

    for (int k0 = 0; k0 < AGGP; k0 += 64) {
        #pragma unroll
        for (int j = 0; j < 2; ++j) {
            int r = 16 * wv + 8 * j + lrow;
            size_t go = (size_t)(row0 + r) * AGGP + k0 + gchunk * 8;
            gl_lds16(Ahg + go, &sAh[16 * wv + 8 * j][0]);
            gl_lds16(Alg + go, &sAl[16 * wv + 8 * j][0]);
        }
        #pragma unroll
        for (int j = 0; j < 4; ++j) {
            int r = 32 * wv + 8 * j + lrow;
            size_t go = (size_t)(col0 + r) * AGGP + k0 + gchunk * 8;
            gl_lds16(Bhg + go, &sBh[32 * wv + 8 * j][0]);
            gl_lds16(Blg + go, &sBl[32 * wv + 8 * j][0]);
        }
        __syncthreads();

        #pragma unroll
        for (int ks = 0; ks < 64; ks += 32) {
            int pcl = ((ks >> 3) + quad) ^ sw;
            short8 ah = *(const short8*)(&sAh[wv * 16 + l16][pcl * 8]);
            short8 al = *(const short8*)(&sAl[wv * 16 + l16][pcl * 8]);
            #pragma unroll
            for (int nt = 0; nt < 8; ++nt) {
                short8 bh = *(const short8*)(&sBh[nt * 16 + l16][pcl * 8]);
                short8 bl = *(const short8*)(&sBl[nt * 16 + l16][pcl * 8]);
                acc[nt] = __builtin_amdgcn_mfma_f32_16x16x32_bf16(ah, bh, acc[nt], 0, 0, 0);
                acc[nt] = __builtin_amdgcn_mfma_f32_16x16x32_bf16(ah, bl, acc[nt], 0, 0, 0);
                acc[nt] = __builtin_amdgcn_mfma_f32_16x16x32_bf16(al, bh, acc[nt], 0, 0, 0);
            }
        }
        __syncthreads();
    }

    int rbase = row0 + wv * 16 + quad * 4;
    #pragma unroll
    for (int nt = 0; nt < 8; ++nt) {
        int c = col0 + nt * 16 + l16;
        #pragma unroll
        for (int i = 0; i < 4; ++i)
            C[(size_t)(rbase + i) * NGRAPH + c] = acc[nt][i] * scale;
    }
}

// ---------------- BN stats reduction (deterministic, two-stage) ----------------

__global__ void k_statred(const float* __restrict__ psum, float* __restrict__ part2, int nrb) {
    int b = blockIdx.x, c = threadIdx.x;   // 768 threads
    float acc = 0.f;
    for (int r = b; r < nrb; r += NRED) acc += psum[(size_t)r * 768 + c];
    part2[b * 768 + c] = acc;
}

__global__ void k_bn_prep(const float* __restrict__ part2, float* __restrict__ stats,
                          const float* __restrict__ gamma, const float* __restrict__ beta,
                          float invN) {
    int c = threadIdx.x;
    if (c >= EMB) return;
    float s = 0.f, q = 0.f;
    for (int b = 0; b < NRED; ++b) {
        s += part2[b * 768 + c];
        q += part2[b * 768 + 384 + c];
    }
    float mean = s * invN;
    float var = q * invN - mean * mean;
    float scale = gamma[c] * rsqrtf(var + BN_EPS);
    stats[c] = scale;
    stats[EMB + c] = beta[c] - mean * scale;
}

// ---------------- fused pool + mean + L2 normalize (proj pitch 320) ----------------

__global__ void k_poolnorm(const bf16* __restrict__ proj, const int* __restrict__ gstart,
                           float* __restrict__ f) {
    int g = blockIdx.x, t = threadIdx.x;
    int s = gstart[g], e = gstart[g + 1];
    float sum = 0.f;
    if (t < EMB)
        for (int r = s; r < e; ++r) sum += b2f(proj[(size_t)r * AGGP + t]);
    float cnt = fmaxf((float)(e - s), 1.f);
    float m = sum / cnt;
    float q = (t < EMB) ? m * m : 0.f;
    for (int off = 32; off > 0; off >>= 1) q += __shfl_down(q, off, 64);
    __shared__ float red[5];
    int lane = t & 63, wid = t >> 6;
    if (lane == 0) red[wid] = q;
    __syncthreads();
    float tot = red[0] + red[1] + red[2] + red[3] + red[4];
    float invn = 1.f / fmaxf(sqrtf(tot), 1e-12f);
    if (t < EMB) f[(size_t)g * EMB + t] = m * invn;
}

// ---------------- host ----------------

static inline int ceil_div(int a, int b) { return (a + b - 1) / b; }

extern "C" void kernel_launch(void* const* d_in, const int* in_sizes, int n_in,
                              void* d_out, int out_size, void* d_ws, size_t ws_size,
                              hipStream_t stream) {
    const int N = in_sizes[0] / 2;    // 100000
    const int E = in_sizes[1] / 2;    // 400000

    const int* x[2]  = { (const int*)d_in[0], (const int*)d_in[4] };
    const int* ei[2] = { (const int*)d_in[1], (const int*)d_in[5] };
    const int* ea[2] = { (const int*)d_in[2], (const int*)d_in[6] };
    const int* bt[2] = { (const int*)d_in[3], (const int*)d_in[7] };
    const float* atom1 = (const float*)d_in[8];
    const float* atom2 = (const float*)d_in[9];
    const float* ee1 = (const float*)d_in[10];   // [5,6,300]
    const float* ee2 = (const float*)d_in[11];   // [5,3,300]
    const float* w1  = (const float*)d_in[12];   // [5,300,600]
    const float* b1  = (const float*)d_in[13];   // [5,600]
    const float* w2  = (const float*)d_in[14];   // [5,600,300]
    const float* b2  = (const float*)d_in[15];   // [5,300]
    const float* gam = (const float*)d_in[16];
    const float* bet = (const float*)d_in[17];
    const float* pw  = (const float*)d_in[18];   // [300,300]
    const float* pb  = (const float*)d_in[19];
    float* out = (float*)d_out;

    // ---- workspace ----
    char* wsb = (char*)d_ws;
    bf16* h    = (bf16*)(wsb);
    bf16* agg  = (bf16*)(wsb + 60000000);
    bf16* hid  = (bf16*)(wsb + 124000000);
    float* guard = (float*)(wsb + 244000000);    // 64 floats, zeroed
    float* f0  = (float*)(wsb + 244000256);
    float* f1  = (float*)(wsb + 248915456);
    // f-splits for logits reuse the (dead) hid region
    unsigned short* f0hi = (unsigned short*)(wsb + 124000000);
    unsigned short* f0lo = (unsigned short*)(wsb + 126621440);
    unsigned short* f1hi = (unsigned short*)(wsb + 129242880);
    unsigned short* f1lo = (unsigned short*)(wsb + 131864320);

    // ---- d_out scratch (consumed before logits GEMM) ----
    int* deg      = (int*)d_out;              // N+1
    int* rowstart = deg + (N + 1);            // N+1
    int* cursor   = rowstart + (N + 1);       // N
    int* esorted  = cursor + N;               // E
    int* packed   = esorted + E;              // E
    int* csum     = packed + E;               // 512
    int* coff     = csum + 512;               // 512
    int* gstart   = coff + 512;               // 4097
    float* stats  = (float*)(gstart + 4097);  // 600
    float* cmb    = stats + 600;              // 18*300
    char* splits  = (char*)d_out + 4500224;   // 256B-aligned
    unsigned short* w1hi = (unsigned short*)(splits);               // 5*[640][320]
    unsigned short* w1lo = (unsigned short*)(splits + 2048000);
    unsigned short* w2hi = (unsigned short*)(splits + 4096000);     // 5*[384][640]
    unsigned short* w2lo = (unsigned short*)(splits + 6553600);
    unsigned short* pjhi = (unsigned short*)(splits + 9011200);     // [384][320]
    unsigned short* pjlo = (unsigned short*)(splits + 9256960);
    float* psum  = (float*)((char*)d_out + 20971520);               // [391][768]
    float* part2 = (float*)((char*)d_out + 25165824);               // [NRED][768]

    const int TB = 256;
    const int nh_blocks = ceil_div(N * EMBC, TB);
    const int na_blocks = ceil_div(N * AGGC, TB);
    const int nchunks = ceil_div(N + 1, 256);
    const float invN = 1.f / (float)N;

    // zero the guard after hid (GEMM2 last-row K-overrun lands here)
    k_zero_f<<<1, 64, 0, stream>>>(guard, 64);

    // ---- split all weights (once; shared by both branches) ----
    for (int l = 0; l < 5; ++l) {
        k_split<<<ceil_div(640 * 320, TB), TB, 0, stream>>>(
            w1 + (size_t)l * EMB * HID, EMB, HID, 320, 640,
            w1hi + (size_t)l * 640 * 320, w1lo + (size_t)l * 640 * 320);
        k_split<<<ceil_div(384 * 640, TB), TB, 0, stream>>>(
            w2 + (size_t)l * HID * EMB, HID, EMB, 640, 384,
            w2hi + (size_t)l * 384 * 640, w2lo + (size_t)l * 384 * 640);
    }
    k_split<<<ceil_div(384 * 320, TB), TB, 0, stream>>>(pw, EMB, EMB, 320, 384, pjhi, pjlo);

    const int mrows = ceil_div(N, GBM);       // 391
    dim3 g1(5, mrows);    // GEMM1: Npad=640
    dim3 g2(3, mrows);    // GEMM2/proj: Npad=384
    dim3 glg(32, 64);     // logits

    for (int br = 0; br < 2; ++br) {
        float* fout = br == 0 ? f0 : f1;
        // ---- CSR build + packed edges (canonical per-bucket order) ----
        k_zero_i<<<ceil_div(N + 1, TB), TB, 0, stream>>>(deg, N + 1);
        k_hist<<<ceil_div(E, TB), TB, 0, stream>>>(ei[br], deg, E);
        k_chunksum<<<nchunks, 256, 0, stream>>>(deg, csum, N + 1);
        k_scanchunks<<<1, 64, 0, stream>>>(csum, coff, nchunks);
        k_scan2<<<nchunks, 256, 0, stream>>>(deg, coff, rowstart, N + 1);
        k_initcursor<<<ceil_div(N, TB), TB, 0, stream>>>(rowstart, cursor, N);
        k_fill<<<ceil_div(E, TB), TB, 0, stream>>>(ei[br], cursor, esorted, E);
        k_pack<<<ceil_div(E, TB), TB, 0, stream>>>(ei[br], ea[br], esorted, packed, E);
        k_sortb<<<ceil_div(N, TB), TB, 0, stream>>>(rowstart, packed, N);
        k_gstart<<<ceil_div(NGRAPH + 1, TB), TB, 0, stream>>>(bt[br], gstart, N);
        // ---- encoder ----
        k_init_h<<<nh_blocks, TB, 0, stream>>>(x[br], (const float4*)atom1,
                                               (const float4*)atom2, (bf4*)h, N);
        for (int l = 0; l < 5; ++l) {
            k_combo<<<ceil_div(18 * EMBC, TB), TB, 0, stream>>>(
                (const float4*)(ee1 + (size_t)l * 6 * EMB),
                (const float4*)(ee2 + (size_t)l * 3 * EMB), (float4*)cmb);
            k_aggregate<<<na_blocks, TB, 0, stream>>>((const bf4*)h, packed,
                                                      (const float4*)cmb, rowstart,
                                                      stats, l > 0, (bf4*)agg, N);
            // GEMM1: [N,320] @ [640,320]^T -> hid [N,600]
            k_gemm_mfma<<<g1, 256, 0, stream>>>(
                (const unsigned short*)agg, AGGP, AGGP,
                w1hi + (size_t)l * 640 * 320, w1lo + (size_t)l * 640 * 320, 320,
                b1 + (size_t)l * HID, (unsigned short*)hid, HID, N, HID, 1,
                nullptr, 0);
            // GEMM2: K 600..639 reads garbage x zero weights = 0
            k_gemm_mfma<<<g2, 256, 0, stream>>>(
                (const unsigned short*)hid, HID, 640,
                w2hi + (size_t)l * 384 * 640, w2lo + (size_t)l * 384 * 640, 640,
                b2 + (size_t)l * EMB, (unsigned short*)h, EMB, N, EMB, 0,
                psum, 1);
            k_statred<<<NRED, 768, 0, stream>>>(psum, part2, mrows);
            k_bn_prep<<<1, 320, 0, stream>>>(part2, stats, gam + (size_t)l * EMB,
                                             bet + (size_t)l * EMB, invN);
        }
        // BN(h) copy (pitch 320, zero-padded) into hid buffer for projector
        k_bncopy<<<na_blocks, TB, 0, stream>>>((const bf4*)h, stats, (bf4*)hid, N);
        // projector: [N,320] @ [384,320]^T -> agg (pitch 320)
        k_gemm_mfma<<<g2, 256, 0, stream>>>(
            (const unsigned short*)hid, AGGP, AGGP,
            pjhi, pjlo, 320, pb, (unsigned short*)agg, AGGP, N, EMB, 0,
            nullptr, 0);
        // fused pool + mean + L2 norm
        k_poolnorm<<<NGRAPH, 320, 0, stream>>>(agg, gstart, fout);
    }
    // ---- logits: split f0/f1 (hid region now dead), 3-pass MFMA ----
    k_fsplit<<<ceil_div(NGRAPH * AGGP, TB), TB, 0, stream>>>(f0, f0hi, f0lo, NGRAPH);
    k_fsplit<<<ceil_div(NGRAPH * AGGP, TB), TB, 0, stream>>>(f1, f1hi, f1lo, NGRAPH);
    k_logits<<<glg, 256, 0, stream>>>(f0hi, f0lo, f1hi, f1lo, out, INV_TEMP);
}

// Round 6
// 4610.449 us; speedup vs baseline: 1.4175x; 1.4175x over previous
//
#include <hip/hip_runtime.h>
#include <hip/hip_bf16.h>

// 5-layer GNN encoder x2 branches + projector + mean-pool + L2norm + logits.
// Round 12: OCCUPANCY is the lever. R5's 256x128 tile (2 blocks/CU) ran
// 1.57x SLOWER than the 128x128 (3 blocks/CU) baseline — GEMM throughput
// scales with resident blocks (latency-bound; cross-block TLP is the only
// latency cover; sync-structure changes R9/R10 were null). Now: tile
// 128x64, GBK=32 dbuf => LDS 32KB => 5 blocks/CU (20 waves), VGPR capped
// via __launch_bounds__(256,5). Per wave/step: 4 staging loads (counted
// vmcnt(4)), 8 ds_read, 16 MFMA. Grid cols double; total MFMA unchanged.
// Per-output k-order + hi/lo chain unchanged => bit-identical (0.421875).
// Determinism machinery from round 8 kept (fixed-slot BN psum + two-stage
// reduce, canonical CSR bucket sort).
//
// d_ws layout (bytes):
//   h    bf16 [N,300]  @ 0            pre-BN layer output
//   agg  bf16 [N,320]  @ 60,000,000   K-padded zeros in 300..319
//   hid  bf16 [N,600]  @ 124,000,000  (reused: BN(h) copy; then f-splits for logits)
//   guard 256B zero    @ 244,000,000  (protects GEMM2 last-row K-overrun)
//   f0   f32  [4096,300] @ 244,000,256
//   f1   f32  [4096,300] @ 248,915,456   total 253,830,656
// d_out doubles as scratch (CSR + packed + stats + combo + split weights +
// psum/part2), all consumed before the final logits GEMM overwrites it.

#define EMB 300
#define EMBC 75       // 300/4 chunks (h pitch 300)
#define AGGP 320      // agg row pitch (elems)
#define AGGC 80
#define HID 600
#define NGRAPH 4096
#define BN_EPS 1e-5f
#define INV_TEMP 25.0f
#define NRED 24       // stage-1 stat-reduction blocks

typedef __hip_bfloat16 bf16;
struct __align__(8) bf4 { bf16 x, y, z, w; };
typedef __attribute__((ext_vector_type(8))) short short8;
typedef __attribute__((ext_vector_type(4))) float float4v;

__device__ inline float b2f(bf16 v) { return __bfloat162float(v); }
__device__ inline bf16 f2b(float v) { return __float2bfloat16(v); }
__device__ inline unsigned short f2bu(float f) {
    bf16 b = __float2bfloat16(f); unsigned short u; __builtin_memcpy(&u, &b, 2); return u;
}

// async global->LDS, 16 bytes per lane; LDS dest = uniform base + lane*16
typedef const unsigned int __attribute__((address_space(1)))* gas_t;
typedef unsigned int __attribute__((address_space(3)))* las_t;
__device__ __forceinline__ void gl_lds16(const unsigned short* g, unsigned short* l) {
    __builtin_amdgcn_global_load_lds((gas_t)g, (las_t)l, 16, 0, 0);
}

// ---------------- small utility ----------------

__global__ void k_zero_f(float* __restrict__ p, int n) {
    int i = blockIdx.x * blockDim.x + threadIdx.x;
    if (i < n) p[i] = 0.f;
}
__global__ void k_zero_i(int* __restrict__ p, int n) {
    int i = blockIdx.x * blockDim.x + threadIdx.x;
    if (i < n) p[i] = 0;
}

// ---------------- weight split: W[K][N] f32 -> Wt_hi/lo[Npad][Kpad] bf16 ----------------

__global__ void k_split(const float* __restrict__ W, int K, int N, int Kpad, int Npad,
                        unsigned short* __restrict__ hi, unsigned short* __restrict__ lo) {
    int idx = blockIdx.x * blockDim.x + threadIdx.x;
    if (idx >= Npad * Kpad) return;
    int n = idx / Kpad, k = idx % Kpad;
    float v = (n < N && k < K) ? W[(size_t)k * N + n] : 0.f;
    bf16 h = __float2bfloat16(v);
    float rem = v - __bfloat162float(h);
    bf16 l = __float2bfloat16(rem);
    unsigned short hu, lu;
    __builtin_memcpy(&hu, &h, 2); __builtin_memcpy(&lu, &l, 2);
    hi[idx] = hu; lo[idx] = lu;
}

// f[G,300] f32 -> hi/lo [G,320] bf16 (pad zero)
__global__ void k_fsplit(const float* __restrict__ f, unsigned short* __restrict__ hi,
                         unsigned short* __restrict__ lo, int G) {
    int idx = blockIdx.x * blockDim.x + threadIdx.x;
    if (idx >= G * AGGP) return;
    int g = idx / AGGP, c = idx % AGGP;
    float v = (c < EMB) ? f[(size_t)g * EMB + c] : 0.f;
    bf16 h = __float2bfloat16(v);
    float rem = v - __bfloat162float(h);
    unsigned short hu; __builtin_memcpy(&hu, &h, 2);
    hi[idx] = hu;
    lo[idx] = f2bu(rem);
}

// ---------------- CSR build (dst-sorted edge ids) ----------------

__global__ void k_hist(const int* __restrict__ ei, int* __restrict__ deg, int E) {
    int e = blockIdx.x * blockDim.x + threadIdx.x;
    if (e < E) atomicAdd(&deg[ei[E + e]], 1);
}

__global__ void k_chunksum(const int* __restrict__ deg, int* __restrict__ csum, int total) {
    __shared__ int s[256];
    int t = threadIdx.x, i = blockIdx.x * 256 + t;
    s[t] = (i < total) ? deg[i] : 0;
    __syncthreads();
    for (int off = 128; off > 0; off >>= 1) {
        if (t < off) s[t] += s[t + off];
        __syncthreads();
    }
    if (t == 0) csum[blockIdx.x] = s[0];
}

__global__ void k_scanchunks(const int* __restrict__ csum, int* __restrict__ coff, int n) {
    if (threadIdx.x == 0) {
        int acc = 0;
        for (int b = 0; b < n; ++b) { coff[b] = acc; acc += csum[b]; }
    }
}

__global__ void k_scan2(const int* __restrict__ deg, const int* __restrict__ coff,
                        int* __restrict__ rowstart, int total) {
    __shared__ int s[256];
    int t = threadIdx.x, b = blockIdx.x, i = b * 256 + t;
    int v = (i < total) ? deg[i] : 0;
    s[t] = v;
    __syncthreads();
    for (int off = 1; off < 256; off <<= 1) {
        int u = (t >= off) ? s[t - off] : 0;
        __syncthreads();
        s[t] += u;
        __syncthreads();
    }
    if (i < total) rowstart[i] = coff[b] + s[t] - v;
}

__global__ void k_initcursor(const int* __restrict__ rowstart, int* __restrict__ cur, int N) {
    int i = blockIdx.x * blockDim.x + threadIdx.x;
    if (i < N) cur[i] = rowstart[i];
}

__global__ void k_fill(const int* __restrict__ ei, int* __restrict__ cur,
                       int* __restrict__ esorted, int E) {
    int e = blockIdx.x * blockDim.x + threadIdx.x;
    if (e < E) {
        int p = atomicAdd(&cur[ei[E + e]], 1);
        esorted[p] = e;
    }
}

// packed[p] = src | (combo<<17), combo = a0*3+a1 (18 combos; self-loop=12)
__global__ void k_pack(const int* __restrict__ ei, const int* __restrict__ ea,
                       const int* __restrict__ esorted, int* __restrict__ packed, int E) {
    int p = blockIdx.x * blockDim.x + threadIdx.x;
    if (p >= E) return;
    int e = esorted[p];
    int s = ei[e];
    int cb = ea[2 * e] * 3 + ea[2 * e + 1];
    packed[p] = s | (cb << 17);
}

// canonical per-bucket order: insertion-sort packed values within each node's
// CSR range -> deterministic fp32 aggregation sum order across calls.
__global__ void k_sortb(const int* __restrict__ rowstart, int* __restrict__ packed, int N) {
    int n = blockIdx.x * blockDim.x + threadIdx.x;
    if (n >= N) return;
    int p0 = rowstart[n], p1 = rowstart[n + 1];
    for (int i = p0 + 1; i < p1; ++i) {
        int v = packed[i];
        int j = i - 1;
        while (j >= p0 && packed[j] > v) { packed[j + 1] = packed[j]; --j; }
        packed[j + 1] = v;
    }
}

__global__ void k_gstart(const int* __restrict__ batch, int* __restrict__ gstart, int N) {
    int g = blockIdx.x * blockDim.x + threadIdx.x;
    if (g > NGRAPH) return;
    int lo = 0, hi = N;
    while (lo < hi) { int mid = (lo + hi) >> 1; if (batch[mid] < g) lo = mid + 1; else hi = mid; }
    gstart[g] = lo;
}

// per-layer combo table: cmb[cb][300] = e1[cb/3] + e2[cb%3]  (fp32)
__global__ void k_combo(const float4* __restrict__ e1, const float4* __restrict__ e2,
                        float4* __restrict__ cmb) {
    int t = blockIdx.x * blockDim.x + threadIdx.x;
    if (t >= 18 * EMBC) return;
    int cb = t / EMBC, j = t % EMBC;
    float4 u = e1[(cb / 3) * EMBC + j];
    float4 v = e2[(cb % 3) * EMBC + j];
    float4 r; r.x = u.x + v.x; r.y = u.y + v.y; r.z = u.z + v.z; r.w = u.w + v.w;
    cmb[t] = r;
}

// ---------------- node init & aggregation (with fused BN affine) ----------------

__global__ void k_init_h(const int* __restrict__ x,
                         const float4* __restrict__ ae1,
                         const float4* __restrict__ ae2,
                         bf4* __restrict__ h4, int N) {
    int idx = blockIdx.x * blockDim.x + threadIdx.x;
    if (idx >= N * EMBC) return;
    int i = idx / EMBC, j = idx % EMBC;
    int a0 = x[2 * i], a1 = x[2 * i + 1];
    float4 u = ae1[a0 * EMBC + j];
    float4 v = ae2[a1 * EMBC + j];
    bf4 r = { f2b(u.x + v.x), f2b(u.y + v.y), f2b(u.z + v.z), f2b(u.w + v.w) };
    h4[idx] = r;
}

// agg[n] = act(h[n]) + cmb[12] + sum_p ( act(h[src(p)]) + cmb[combo(p)] )
__global__ void k_aggregate(const bf4* __restrict__ h4,
                            const int* __restrict__ packed,
                            const float4* __restrict__ cmb,   // [18,75]
                            const int* __restrict__ rowstart,
                            const float* __restrict__ stats, int use_aff,
                            bf4* __restrict__ agg4, int N) {
    int idx = blockIdx.x * blockDim.x + threadIdx.x;
    if (idx >= N * AGGC) return;
    int n = idx / AGGC, j = idx % AGGC;
    if (j >= EMBC) {
        bf4 z = { f2b(0.f), f2b(0.f), f2b(0.f), f2b(0.f) };
        agg4[idx] = z;
        return;
    }
    float4 sc = make_float4(1.f, 1.f, 1.f, 1.f);
    float4 sh = make_float4(0.f, 0.f, 0.f, 0.f);
    if (use_aff) {
        sc = ((const float4*)stats)[j];
        sh = ((const float4*)(stats + EMB))[j];
    }
    bf4 hv = h4[(size_t)n * EMBC + j];
    float hx = b2f(hv.x), hy = b2f(hv.y), hz = b2f(hv.z), hw = b2f(hv.w);
    if (use_aff) {
        hx = fmaxf(hx * sc.x + sh.x, 0.f); hy = fmaxf(hy * sc.y + sh.y, 0.f);
        hz = fmaxf(hz * sc.z + sh.z, 0.f); hw = fmaxf(hw * sc.w + sh.w, 0.f);
    }
    float4 s0 = cmb[12 * EMBC + j];      // self-loop combo (edge_attr [4,0])
    float ax = hx + s0.x, ay = hy + s0.y, az = hz + s0.z, aw = hw + s0.w;
    int p0 = rowstart[n], p1 = rowstart[n + 1];
    for (int p = p0; p < p1; ++p) {
        int u = packed[p];
        int s = u & 131071;
        int cb = u >> 17;
        bf4 hs = h4[(size_t)s * EMBC + j];
        float gx = b2f(hs.x), gy = b2f(hs.y), gz = b2f(hs.z), gw = b2f(hs.w);
        if (use_aff) {
            gx = fmaxf(gx * sc.x + sh.x, 0.f); gy = fmaxf(gy * sc.y + sh.y, 0.f);
            gz = fmaxf(gz * sc.z + sh.z, 0.f); gw = fmaxf(gw * sc.w + sh.w, 0.f);
        }
        float4 cv = cmb[cb * EMBC + j];
        ax += gx + cv.x; ay += gy + cv.y;
        az += gz + cv.z; aw += gw + cv.w;
    }
    bf4 r = { f2b(ax), f2b(ay), f2b(az), f2b(aw) };
    agg4[idx] = r;
}

// BN(h) copy for projector: dst[N,320] = scale*h + shift (no relu), pad zeroed
__global__ void k_bncopy(const bf4* __restrict__ h4, const float* __restrict__ stats,
                         bf4* __restrict__ dst, int N) {
    int idx = blockIdx.x * blockDim.x + threadIdx.x;
    if (idx >= N * AGGC) return;
    int n = idx / AGGC, j = idx % AGGC;
    if (j >= EMBC) {
        bf4 z = { f2b(0.f), f2b(0.f), f2b(0.f), f2b(0.f) };
        dst[idx] = z;
        return;
    }
    float4 sc = ((const float4*)stats)[j];
    float4 sh = ((const float4*)(stats + EMB))[j];
    bf4 v = h4[(size_t)n * EMBC + j];
    bf4 r = { f2b(b2f(v.x) * sc.x + sh.x), f2b(b2f(v.y) * sc.y + sh.y),
              f2b(b2f(v.z) * sc.z + sh.z), f2b(b2f(v.w) * sc.w + sh.w) };
    dst[idx] = r;
}

// ---------------- MFMA GEMM: C_bf16[M,Nc] = A_bf16[M,K] @ (Bhi+Blo)^T + bias --------
// Round 12: tile 128x64, GBK=32 dbuf (32 KB LDS => 5 blocks/CU; launch
// bounds cap VGPR for 5 waves/SIMD). 4 waves in 2x2 grid of 64x32 tiles
// (acc[4][2]). Counted-vmcnt loop: 4 gl_lds16/wave/step; wait vmcnt(4).
// 64B-row LDS swizzle: store chunk (lane&3)^((lane>>3)&3); read
// pc = quad^((l16>>1)&3). Per-output-element FP sequence identical to
// rounds 9-11 (same k order, same hi/lo chain) => bit-identical output.

#define GBM 128
#define GBN 64
#define GBK 32

__global__ __launch_bounds__(256, 5)
void k_gemm_mfma(const unsigned short* __restrict__ A, int lda, int Kpad,
                 const unsigned short* __restrict__ Bhi,
                 const unsigned short* __restrict__ Blo, int ldb,
                 const float* __restrict__ bias,
                 unsigned short* __restrict__ C, int ldc, int M, int Nc, int relu,
                 float* __restrict__ psum, int do_stats) {
    __shared__ unsigned short As[2][GBM][GBK];   // 16 KB (reused as cred)
    __shared__ unsigned short Bh[2][GBN][GBK];   // 8 KB
    __shared__ unsigned short Bl[2][GBN][GBK];   // 8 KB

    int tid = threadIdx.x;
    int wv = tid >> 6, lane = tid & 63;
    int quad = lane >> 4, l16 = lane & 15;
    int wm = wv & 1, wn = wv >> 1;            // 2x2 wave grid of 64x32 tiles

    // staging lane mapping: 4 lanes/row, chunk XOR-swizzled by row pair
    int srow = lane >> 2;                     // 0..15
    int gch = (lane & 3) ^ ((lane >> 3) & 3); // global 8-elem chunk
    // read swizzle
    int pc = quad ^ ((l16 >> 1) & 3);

    // XCD swizzle: col-tiles of one row-block get linear ids equal mod 8
    int ncols = gridDim.x, nrows = gridDim.y;
    int lin = blockIdx.y * ncols + blockIdx.x;
    int g = lin / (8 * ncols);
    int rem = lin - g * 8 * ncols;
    int rows_in = min(8, nrows - g * 8);
    int colb = rem / rows_in;
    int rowb = g * 8 + (rem - colb * rows_in);
    int row0 = rowb * GBM;
    int col0 = colb * GBN;

    // per-lane staging source bases: wave wv stages A rows [32wv,32wv+32),
    // B rows [16wv,16wv+16)
    const unsigned short* Asrc[2];
    #pragma unroll
    for (int j = 0; j < 2; ++j) {
        int r = 32 * wv + 16 * j + srow;
        Asrc[j] = A + (size_t)min(row0 + r, M - 1) * lda + gch * 8;
    }
    const unsigned short* Bsrc = Bhi + (size_t)(col0 + 16 * wv + srow) * ldb + gch * 8;
    const size_t dBL = (size_t)(Blo - Bhi);

    float4v acc[4][2];
    #pragma unroll
    for (int i = 0; i < 4; ++i)
        #pragma unroll
        for (int j = 0; j < 2; ++j) acc[i][j] = (float4v){0.f, 0.f, 0.f, 0.f};

    const int ntk = Kpad / GBK;

    // prologue: stage tiles 0 and 1 (8 loads in flight per wave)
    gl_lds16(Asrc[0], &As[0][32 * wv][0]);
    gl_lds16(Asrc[1], &As[0][32 * wv + 16][0]);
    gl_lds16(Bsrc, &Bh[0][16 * wv][0]);
    gl_lds16(Bsrc + dBL, &Bl[0][16 * wv][0]);
    if (ntk > 1) {
        gl_lds16(Asrc[0] + GBK, &As[1][32 * wv][0]);
        gl_lds16(Asrc[1] + GBK, &As[1][32 * wv + 16][0]);
        gl_lds16(Bsrc + GBK, &Bh[1][16 * wv][0]);
        gl_lds16(Bsrc + GBK + dBL, &Bl[1][16 * wv][0]);
    }

    for (int t = 0; t < ntk; ++t) {
        int cur = t & 1;
        // wait own tile-t loads (4); tile-t+1's 4 stay in flight
        if (t + 1 < ntk) {
            asm volatile("s_waitcnt vmcnt(4)" ::: "memory");
        } else {
            asm volatile("s_waitcnt vmcnt(0)" ::: "memory");
        }
        __builtin_amdgcn_s_barrier();          // all waves' tile-t in LDS
        __builtin_amdgcn_sched_barrier(0);
        // compute current tile: wave (wm,wn) rows [64wm..+64) x cols [32wn..+32)
        short8 a[4];
        #pragma unroll
        for (int mt = 0; mt < 4; ++mt)
            a[mt] = *(const short8*)(&As[cur][64 * wm + mt * 16 + l16][pc * 8]);
        #pragma unroll
        for (int ntl = 0; ntl < 2; ++ntl) {
            short8 bh = *(const short8*)(&Bh[cur][32 * wn + ntl * 16 + l16][pc * 8]);
            short8 bl = *(const short8*)(&Bl[cur][32 * wn + ntl * 16 + l16][pc * 8]);
            #pragma unroll
            for (int mt = 0; mt < 4; ++mt) {
                acc[mt][ntl] = __builtin_amdgcn_mfma_f32_16x16x32_bf16(a[mt], bh, acc[mt][ntl], 0, 0, 0);
                acc[mt][ntl] = __builtin_amdgcn_mfma_f32_16x16x32_bf16(a[mt], bl, acc[mt][ntl], 0, 0, 0);
            }
        }
        __builtin_amdgcn_s_barrier();          // all waves done reading buf[cur]
        __builtin_amdgcn_sched_barrier(0);
        // restage consumed buffer with tile t+2 (in flight across next barrier)
        if (t + 2 < ntk) {
            int k2 = (t + 2) * GBK;
            gl_lds16(Asrc[0] + k2, &As[cur][32 * wv][0]);
            gl_lds16(Asrc[1] + k2, &As[cur][32 * wv + 16][0]);
            gl_lds16(Bsrc + k2, &Bh[cur][16 * wv][0]);
            gl_lds16(Bsrc + k2 + dBL, &Bl[cur][16 * wv][0]);
        }
    }

    // epilogue: C/D layout col=lane&15, row=quad*4+reg
    float sv[2], qv[2];
    #pragma unroll
    for (int ntl = 0; ntl < 2; ++ntl) { sv[ntl] = 0.f; qv[ntl] = 0.f; }
    #pragma unroll
    for (int mt = 0; mt < 4; ++mt) {
        int rbase = row0 + 64 * wm + mt * 16 + quad * 4;
        #pragma unroll
        for (int ntl = 0; ntl < 2; ++ntl) {
            int c = col0 + 32 * wn + ntl * 16 + l16;
            if (c >= Nc) continue;
            float bs = bias[c];
            #pragma unroll
            for (int i = 0; i < 4; ++i) {
                int r = rbase + i;
                if (r >= M) continue;
                float v = acc[mt][ntl][i] + bs;
                if (relu) v = fmaxf(v, 0.f);
                if (do_stats) { sv[ntl] += v; qv[ntl] += v * v; }
                C[(size_t)r * ldc + c] = f2bu(v);
            }
        }
    }
    if (do_stats) {
        float* cred = (float*)(&As[0][0][0]);   // 4 waves x 32 s + 4 waves x 32 q
        #pragma unroll
        for (int ntl = 0; ntl < 2; ++ntl) {
            float s = sv[ntl], q = qv[ntl];
            s += __shfl_down(s, 32, 64); s += __shfl_down(s, 16, 64);
            q += __shfl_down(q, 32, 64); q += __shfl_down(q, 16, 64);
            if (quad == 0) {
                cred[wv * 64 + ntl * 16 + l16] = s;
                cred[256 + wv * 64 + ntl * 16 + l16] = q;
            }
        }
        __syncthreads();
        if (tid < 64) {
            // per-row-block partial: psum[rowb][c] = s, psum[rowb][384+c] = q
            // col group g = tid>>5 (wn), waves wv = 2g (rows 0-63) then 2g+1
            int gc = tid >> 5, cin = tid & 31;
            float s = cred[(2 * gc) * 64 + cin] + cred[(2 * gc + 1) * 64 + cin];
            float q = cred[256 + (2 * gc) * 64 + cin] + cred[256 + (2 * gc + 1) * 64 + cin];
            int c = col0 + tid;
            psum[(size_t)rowb * 768 + c] = s;
            psum[(size_t)rowb * 768 + 384 + c] = q;
        }
    }
}

// ---------------- logits MFMA: out = scale * (Ah+Al) @ (Bh+Bl)^T  (ll skipped) ----

__global__ __launch_bounds__(256)
void k_logits(const unsigned short* __restrict__ Ahg, const unsigned short* __restrict__ Alg,
              const unsigned short* __restrict__ Bhg, const unsigned short* __restrict__ Blg,
              float* __restrict__ C, float scale) {
    __shared__ unsigned short sAh[64][64];
    __shared__ unsigned short sAl[64][64];
    __shared__ unsigned short sBh[128][64];
    __shared__ unsigned short sBl[128][64];

    int tid = threadIdx.x;
    int wv = tid >> 6, lane = tid & 63;
    int quad = lane >> 4, l16 = lane & 15;
    int lrow = lane >> 3;
    int gchunk = (lane & 7) ^ lrow;
    int sw = lane & 7;
    int row0 = blockIdx.y * 64;
    int col0 = blockIdx.x * 128;

    float4v acc[8];
    #pragma unroll
    for (int j = 0; j < 8; ++j) acc[j] = (float4v){0.f, 0.f, 0.f, 0.f};

    for (int k0 = 0; k0 < AGGP; k0 += 64) {
        #pragma unroll
        for (int j = 0; j < 2; ++j) {
            int r = 16 * wv + 8 * j + lrow;
            size_t go = (size_t)(row0 + r) * AGGP + k0 + gchunk * 8;
            gl_lds16(Ahg + go, &sAh[16 * wv + 8 * j][0]);
            gl_lds16(Alg + go, &sAl[16 * wv + 8 * j][0]);
        }
        #pragma unroll
        for (int j = 0; j < 4; ++j) {
            int r = 32 * wv + 8 * j + lrow;
            size_t go = (size_t)(col0 + r) * AGGP + k0 + gchunk * 8;
            gl_lds16(Bhg + go, &sBh[32 * wv + 8 * j][0]);
            gl_lds16(Blg + go, &sBl[32 * wv + 8 * j][0]);
        }
        __syncthreads();

        #pragma unroll
        for (int ks = 0; ks < 64; ks += 32) {
            int pcl = ((ks >> 3) + quad) ^ sw;
            short8 ah = *(const short8*)(&sAh[wv * 16 + l16][pcl * 8]);
            short8 al = *(const short8*)(&sAl[wv * 16 + l16][pcl * 8]);
            #pragma unroll
            for (int nt = 0; nt < 8; ++nt) {
                short8 bh = *(const short8*)(&sBh[nt * 16 + l16][pcl * 8]);
                short8 bl = *(const short8*)(&sBl[nt * 16 + l16][pcl * 8]);
                acc[nt] = __builtin_amdgcn_mfma_f32_16x16x32_bf16(ah, bh, acc[nt], 0, 0, 0);
                acc[nt] = __builtin_amdgcn_mfma_f32_16x16x32_bf16(ah, bl, acc[nt], 0, 0, 0);
                acc[nt] = __builtin_amdgcn_mfma_f32_16x16x32_bf16(al, bh, acc[nt], 0, 0, 0);
            }
        }
        __syncthreads();
    }

    int rbase = row0 + wv * 16 + quad * 4;
    #pragma unroll
    for (int nt = 0; nt < 8; ++nt) {
        int c = col0 + nt * 16 + l16;
        #pragma unroll
        for (int i = 0; i < 4; ++i)
            C[(size_t)(rbase + i) * NGRAPH + c] = acc[nt][i] * scale;
    }
}

// ---------------- BN stats reduction (deterministic, two-stage) ----------------

__global__ void k_statred(const float* __restrict__ psum, float* __restrict__ part2, int nrb) {
    int b = blockIdx.x, c = threadIdx.x;   // 768 threads
    float acc = 0.f;
    for (int r = b; r < nrb; r += NRED) acc += psum[(size_t)r * 768 + c];
    part2[b * 768 + c] = acc;
}

__global__ void k_bn_prep(const float* __restrict__ part2, float* __restrict__ stats,
                          const float* __restrict__ gamma, const float* __restrict__ beta,
                          float invN) {
    int c = threadIdx.x;
    if (c >= EMB) return;
    float s = 0.f, q = 0.f;
    for (int b = 0; b < NRED; ++b) {
        s += part2[b * 768 + c];
        q += part2[b * 768 + 384 + c];
    }
    float mean = s * invN;
    float var = q * invN - mean * mean;
    float scale = gamma[c] * rsqrtf(var + BN_EPS);
    stats[c] = scale;
    stats[EMB + c] = beta[c] - mean * scale;
}

// ---------------- fused pool + mean + L2 normalize (proj pitch 320) ----------------

__global__ void k_poolnorm(const bf16* __restrict__ proj, const int* __restrict__ gstart,
                           float* __restrict__ f) {
    int g = blockIdx.x, t = threadIdx.x;
    int s = gstart[g], e = gstart[g + 1];
    float sum = 0.f;
    if (t < EMB)
        for (int r = s; r < e; ++r) sum += b2f(proj[(size_t)r * AGGP + t]);
    float cnt = fmaxf((float)(e - s), 1.f);
    float m = sum / cnt;
    float q = (t < EMB) ? m * m : 0.f;
    for (int off = 32; off > 0; off >>= 1) q += __shfl_down(q, off, 64);
    __shared__ float red[5];
    int lane = t & 63, wid = t >> 6;
    if (lane == 0) red[wid] = q;
    __syncthreads();
    float tot = red[0] + red[1] + red[2] + red[3] + red[4];
    float invn = 1.f / fmaxf(sqrtf(tot), 1e-12f);
    if (t < EMB) f[(size_t)g * EMB + t] = m * invn;
}

// ---------------- host ----------------

static inline int ceil_div(int a, int b) { return (a + b - 1) / b; }

extern "C" void kernel_launch(void* const* d_in, const int* in_sizes, int n_in,
                              void* d_out, int out_size, void* d_ws, size_t ws_size,
                              hipStream_t stream) {
    const int N = in_sizes[0] / 2;    // 100000
    const int E = in_sizes[1] / 2;    // 400000

    const int* x[2]  = { (const int*)d_in[0], (const int*)d_in[4] };
    const int* ei[2] = { (const int*)d_in[1], (const int*)d_in[5] };
    const int* ea[2] = { (const int*)d_in[2], (const int*)d_in[6] };
    const int* bt[2] = { (const int*)d_in[3], (const int*)d_in[7] };
    const float* atom1 = (const float*)d_in[8];
    const float* atom2 = (const float*)d_in[9];
    const float* ee1 = (const float*)d_in[10];   // [5,6,300]
    const float* ee2 = (const float*)d_in[11];   // [5,3,300]
    const float* w1  = (const float*)d_in[12];   // [5,300,600]
    const float* b1  = (const float*)d_in[13];   // [5,600]
    const float* w2  = (const float*)d_in[14];   // [5,600,300]
    const float* b2  = (const float*)d_in[15];   // [5,300]
    const float* gam = (const float*)d_in[16];
    const float* bet = (const float*)d_in[17];
    const float* pw  = (const float*)d_in[18];   // [300,300]
    const float* pb  = (const float*)d_in[19];
    float* out = (float*)d_out;

    // ---- workspace ----
    char* wsb = (char*)d_ws;
    bf16* h    = (bf16*)(wsb);
    bf16* agg  = (bf16*)(wsb + 60000000);
    bf16* hid  = (bf16*)(wsb + 124000000);
    float* guard = (float*)(wsb + 244000000);    // 64 floats, zeroed
    float* f0  = (float*)(wsb + 244000256);
    float* f1  = (float*)(wsb + 248915456);
    // f-splits for logits reuse the (dead) hid region
    unsigned short* f0hi = (unsigned short*)(wsb + 124000000);
    unsigned short* f0lo = (unsigned short*)(wsb + 126621440);
    unsigned short* f1hi = (unsigned short*)(wsb + 129242880);
    unsigned short* f1lo = (unsigned short*)(wsb + 131864320);

    // ---- d_out scratch (consumed before logits GEMM) ----
    int* deg      = (int*)d_out;              // N+1
    int* rowstart = deg + (N + 1);            // N+1
    int* cursor   = rowstart + (N + 1);       // N
    int* esorted  = cursor + N;               // E
    int* packed   = esorted + E;              // E
    int* csum     = packed + E;               // 512
    int* coff     = csum + 512;               // 512
    int* gstart   = coff + 512;               // 4097
    float* stats  = (float*)(gstart + 4097);  // 600
    float* cmb    = stats + 600;              // 18*300
    char* splits  = (char*)d_out + 4500224;   // 256B-aligned
    unsigned short* w1hi = (unsigned short*)(splits);               // 5*[640][320]
    unsigned short* w1lo = (unsigned short*)(splits + 2048000);
    unsigned short* w2hi = (unsigned short*)(splits + 4096000);     // 5*[384][640]
    unsigned short* w2lo = (unsigned short*)(splits + 6553600);
    unsigned short* pjhi = (unsigned short*)(splits + 9011200);     // [384][320]
    unsigned short* pjlo = (unsigned short*)(splits + 9256960);
    float* psum  = (float*)((char*)d_out + 20971520);               // [782][768]
    float* part2 = (float*)((char*)d_out + 25165824);               // [NRED][768]

    const int TB = 256;
    const int nh_blocks = ceil_div(N * EMBC, TB);
    const int na_blocks = ceil_div(N * AGGC, TB);
    const int nchunks = ceil_div(N + 1, 256);
    const float invN = 1.f / (float)N;

    // zero the guard after hid (GEMM2 last-row K-overrun lands here)
    k_zero_f<<<1, 64, 0, stream>>>(guard, 64);

    // ---- split all weights (once; shared by both branches) ----
    for (int l = 0; l < 5; ++l) {
        k_split<<<ceil_div(640 * 320, TB), TB, 0, stream>>>(
            w1 + (size_t)l * EMB * HID, EMB, HID, 320, 640,
            w1hi + (size_t)l * 640 * 320, w1lo + (size_t)l * 640 * 320);
        k_split<<<ceil_div(384 * 640, TB), TB, 0, stream>>>(
            w2 + (size_t)l * HID * EMB, HID, EMB, 640, 384,
            w2hi + (size_t)l * 384 * 640, w2lo + (size_t)l * 384 * 640);
    }
    k_split<<<ceil_div(384 * 320, TB), TB, 0, stream>>>(pw, EMB, EMB, 320, 384, pjhi, pjlo);

    const int mrows = ceil_div(N, GBM);       // 782
    dim3 g1(10, mrows);   // GEMM1: Npad=640, 64-col tiles
    dim3 g2(6, mrows);    // GEMM2/proj: Npad=384
    dim3 glg(32, 64);     // logits

    for (int br = 0; br < 2; ++br) {
        float* fout = br == 0 ? f0 : f1;
        // ---- CSR build + packed edges (canonical per-bucket order) ----
        k_zero_i<<<ceil_div(N + 1, TB), TB, 0, stream>>>(deg, N + 1);
        k_hist<<<ceil_div(E, TB), TB, 0, stream>>>(ei[br], deg, E);
        k_chunksum<<<nchunks, 256, 0, stream>>>(deg, csum, N + 1);
        k_scanchunks<<<1, 64, 0, stream>>>(csum, coff, nchunks);
        k_scan2<<<nchunks, 256, 0, stream>>>(deg, coff, rowstart, N + 1);
        k_initcursor<<<ceil_div(N, TB), TB, 0, stream>>>(rowstart, cursor, N);
        k_fill<<<ceil_div(E, TB), TB, 0, stream>>>(ei[br], cursor, esorted, E);
        k_pack<<<ceil_div(E, TB), TB, 0, stream>>>(ei[br], ea[br], esorted, packed, E);
        k_sortb<<<ceil_div(N, TB), TB, 0, stream>>>(rowstart, packed, N);
        k_gstart<<<ceil_div(NGRAPH + 1, TB), TB, 0, stream>>>(bt[br], gstart, N);
        // ---- encoder ----
        k_init_h<<<nh_blocks, TB, 0, stream>>>(x[br], (const float4*)atom1,
                                               (const float4*)atom2, (bf4*)h, N);
        for (int l = 0; l < 5; ++l) {
            k_combo<<<ceil_div(18 * EMBC, TB), TB, 0, stream>>>(
                (const float4*)(ee1 + (size_t)l * 6 * EMB),
                (const float4*)(ee2 + (size_t)l * 3 * EMB), (float4*)cmb);
            k_aggregate<<<na_blocks, TB, 0, stream>>>((const bf4*)h, packed,
                                                      (const float4*)cmb, rowstart,
                                                      stats, l > 0, (bf4*)agg, N);
            // GEMM1: [N,320] @ [640,320]^T -> hid [N,600]
            k_gemm_mfma<<<g1, 256, 0, stream>>>(
                (const unsigned short*)agg, AGGP, AGGP,
                w1hi + (size_t)l * 640 * 320, w1lo + (size_t)l * 640 * 320, 320,
                b1 + (size_t)l * HID, (unsigned short*)hid, HID, N, HID, 1,
                nullptr, 0);
            // GEMM2: K 600..639 reads garbage x zero weights = 0
            k_gemm_mfma<<<g2, 256, 0, stream>>>(
                (const unsigned short*)hid, HID, 640,
                w2hi + (size_t)l * 384 * 640, w2lo + (size_t)l * 384 * 640, 640,
                b2 + (size_t)l * EMB, (unsigned short*)h, EMB, N, EMB, 0,
                psum, 1);
            k_statred<<<NRED, 768, 0, stream>>>(psum, part2, mrows);
            k_bn_prep<<<1, 320, 0, stream>>>(part2, stats, gam + (size_t)l * EMB,
                                             bet + (size_t)l * EMB, invN);
        }
        // BN(h) copy (pitch 320, zero-padded) into hid buffer for projector
        k_bncopy<<<na_blocks, TB, 0, stream>>>((const bf4*)h, stats, (bf4*)hid, N);
        // projector: [N,320] @ [384,320]^T -> agg (pitch 320)
        k_gemm_mfma<<<g2, 256, 0, stream>>>(
            (const unsigned short*)hid, AGGP, AGGP,
            pjhi, pjlo, 320, pb, (unsigned short*)agg, AGGP, N, EMB, 0,
            nullptr, 0);
        // fused pool + mean + L2 norm
        k_poolnorm<<<NGRAPH, 320, 0, stream>>>(agg, gstart, fout);
    }
    // ---- logits: split f0/f1 (hid region now dead), 3-pass MFMA ----
    k_fsplit<<<ceil_div(NGRAPH * AGGP, TB), TB, 0, stream>>>(f0, f0hi, f0lo, NGRAPH);
    k_fsplit<<<ceil_div(NGRAPH * AGGP, TB), TB, 0, stream>>>(f1, f1hi, f1lo, NGRAPH);
    k_logits<<<glg, 256, 0, stream>>>(f0hi, f0lo, f1hi, f1lo, out, INV_TEMP);
}